// Round 1
// baseline (850.227 us; speedup 1.0000x reference)
//
#include <hip/hip_runtime.h>
#include <math.h>

#define DF 64

__device__ __forceinline__ float rlane(float v, int l) {
  return __int_as_float(__builtin_amdgcn_readlane(__float_as_int(v), l));
}

__global__ __launch_bounds__(256) void zero_int_kernel(int* __restrict__ p, int n) {
  int i = blockIdx.x * 256 + threadIdx.x;
  if (i < n) p[i] = 0;
}

__global__ __launch_bounds__(256) void deg_kernel(const int* __restrict__ dst,
                                                  int* __restrict__ deg, int e) {
  int i = blockIdx.x * 256 + threadIdx.x;
  if (i < e) atomicAdd(&deg[dst[i]], 1);
}

// single-block exclusive scan over n counts -> rowp[0..n], also copies to curs
__global__ __launch_bounds__(1024) void scan_kernel(const int* __restrict__ deg,
                                                    int* __restrict__ rowp,
                                                    int* __restrict__ curs, int n) {
  __shared__ int a[1024];
  const int t = threadIdx.x;
  int carry = 0;
  for (int base = 0; base < n; base += 1024) {
    int i = base + t;
    int v = (i < n) ? deg[i] : 0;
    a[t] = v;
    __syncthreads();
    for (int off = 1; off < 1024; off <<= 1) {
      int addv = (t >= off) ? a[t - off] : 0;
      __syncthreads();
      a[t] += addv;
      __syncthreads();
    }
    if (i < n) {
      int excl = carry + a[t] - v;
      rowp[i] = excl;
      curs[i] = excl;
    }
    carry += a[1023];
    __syncthreads();
  }
  if (t == 0) rowp[n] = carry;
}

__global__ __launch_bounds__(256) void fill_kernel(const int* __restrict__ src,
                                                   const int* __restrict__ dst,
                                                   int* __restrict__ curs,
                                                   int* __restrict__ csr, int e) {
  int i = blockIdx.x * 256 + threadIdx.x;
  if (i < e) {
    int p = atomicAdd(&curs[dst[i]], 1);
    csr[p] = src[i];
  }
}

// Wc[l][k][c] = sum_t W[l][k][t] * w_ih[c][t]   (combined message->input-gate weights)
__global__ __launch_bounds__(256) void wc_kernel(const float* __restrict__ W,
                                                 const float* __restrict__ w_ih,
                                                 float* __restrict__ Wc, int total) {
  int idx = blockIdx.x * 256 + threadIdx.x;
  if (idx >= total) return;
  int c = idx % 192;
  int kl = idx / 192;  // l*64 + k
  const float* wr = W + (size_t)kl * 64;
  const float* ir = w_ih + (size_t)c * 64;
  float s = 0.f;
#pragma unroll
  for (int t2 = 0; t2 < 64; ++t2) s = fmaf(wr[t2], ir[t2], s);
  Wc[idx] = s;
}

// WhT[k][c] = w_hh[c][k]
__global__ __launch_bounds__(256) void wht_kernel(const float* __restrict__ w_hh,
                                                  float* __restrict__ WhT) {
  int idx = blockIdx.x * 256 + threadIdx.x;
  if (idx >= 64 * 192) return;
  int c = idx % 192, k = idx / 192;
  WhT[idx] = w_hh[(size_t)c * 64 + k];
}

// one wave per node: segH[n][lane] = sum over incoming edges of h[src][lane]
__global__ __launch_bounds__(256) void gather_kernel(const float* __restrict__ h,
                                                     const int* __restrict__ rowp,
                                                     const int* __restrict__ csr,
                                                     float* __restrict__ segH, int n) {
  int gw = (int)((blockIdx.x * 256 + threadIdx.x) >> 6);
  int lane = threadIdx.x & 63;
  if (gw >= n) return;
  int beg = rowp[gw], end = rowp[gw + 1];
  float acc = 0.f;
  int e = beg;
  for (; e + 4 <= end; e += 4) {
    int s0 = csr[e], s1 = csr[e + 1], s2 = csr[e + 2], s3 = csr[e + 3];
    float v0 = h[(size_t)s0 * DF + lane];
    float v1 = h[(size_t)s1 * DF + lane];
    float v2 = h[(size_t)s2 * DF + lane];
    float v3 = h[(size_t)s3 * DF + lane];
    acc += v0 + v1 + v2 + v3;
  }
  for (; e < end; ++e) acc += h[(size_t)csr[e] * DF + lane];
  segH[(size_t)gw * DF + lane] = acc;
}

// fused GRU: gi = segH @ Wc + b_ih ; gh = h @ w_hh^T + b_hh ; gates ; h'
// weights in LDS, 4 nodes per wave, readlane broadcasts.
__global__ __launch_bounds__(1024, 1) void gru_kernel(
    const float* __restrict__ segH, const float* __restrict__ hin,
    const float* __restrict__ Wc, const float* __restrict__ WhT,
    const float* __restrict__ bih, const float* __restrict__ bhh,
    float* __restrict__ hout, int n) {
  __shared__ float sWc[64 * 192];
  __shared__ float sWh[64 * 192];
  for (int i = threadIdx.x; i < 64 * 192; i += 1024) {
    sWc[i] = Wc[i];
    sWh[i] = WhT[i];
  }
  __syncthreads();
  const int lane = threadIdx.x & 63;
  const int wid = threadIdx.x >> 6;  // 0..15
  const float bir = bih[lane], biz = bih[64 + lane], bin_ = bih[128 + lane];
  const float bhr = bhh[lane], bhz = bhh[64 + lane], bhn = bhh[128 + lane];

  for (int tile = blockIdx.x * 64; tile < n; tile += gridDim.x * 64) {
    const int nb = tile + wid * 4;
    float a0 = 0.f, a1 = 0.f, a2 = 0.f, a3 = 0.f;
    float h0 = 0.f, h1 = 0.f, h2 = 0.f, h3 = 0.f;
    if (nb + 0 < n) { a0 = segH[(size_t)(nb + 0) * DF + lane]; h0 = hin[(size_t)(nb + 0) * DF + lane]; }
    if (nb + 1 < n) { a1 = segH[(size_t)(nb + 1) * DF + lane]; h1 = hin[(size_t)(nb + 1) * DF + lane]; }
    if (nb + 2 < n) { a2 = segH[(size_t)(nb + 2) * DF + lane]; h2 = hin[(size_t)(nb + 2) * DF + lane]; }
    if (nb + 3 < n) { a3 = segH[(size_t)(nb + 3) * DF + lane]; h3 = hin[(size_t)(nb + 3) * DF + lane]; }

    float i0r = bir, i0z = biz, i0n = bin_, g0r = bhr, g0z = bhz, g0n = bhn;
    float i1r = bir, i1z = biz, i1n = bin_, g1r = bhr, g1z = bhz, g1n = bhn;
    float i2r = bir, i2z = biz, i2n = bin_, g2r = bhr, g2z = bhz, g2n = bhn;
    float i3r = bir, i3z = biz, i3n = bin_, g3r = bhr, g3z = bhz, g3n = bhn;

#pragma unroll 8
    for (int k = 0; k < 64; ++k) {
      const float wcr = sWc[k * 192 + lane];
      const float wcz = sWc[k * 192 + 64 + lane];
      const float wcn = sWc[k * 192 + 128 + lane];
      const float whr = sWh[k * 192 + lane];
      const float whz = sWh[k * 192 + 64 + lane];
      const float whn = sWh[k * 192 + 128 + lane];
      float ak, hk;
      ak = rlane(a0, k); hk = rlane(h0, k);
      i0r = fmaf(ak, wcr, i0r); i0z = fmaf(ak, wcz, i0z); i0n = fmaf(ak, wcn, i0n);
      g0r = fmaf(hk, whr, g0r); g0z = fmaf(hk, whz, g0z); g0n = fmaf(hk, whn, g0n);
      ak = rlane(a1, k); hk = rlane(h1, k);
      i1r = fmaf(ak, wcr, i1r); i1z = fmaf(ak, wcz, i1z); i1n = fmaf(ak, wcn, i1n);
      g1r = fmaf(hk, whr, g1r); g1z = fmaf(hk, whz, g1z); g1n = fmaf(hk, whn, g1n);
      ak = rlane(a2, k); hk = rlane(h2, k);
      i2r = fmaf(ak, wcr, i2r); i2z = fmaf(ak, wcz, i2z); i2n = fmaf(ak, wcn, i2n);
      g2r = fmaf(hk, whr, g2r); g2z = fmaf(hk, whz, g2z); g2n = fmaf(hk, whn, g2n);
      ak = rlane(a3, k); hk = rlane(h3, k);
      i3r = fmaf(ak, wcr, i3r); i3z = fmaf(ak, wcz, i3z); i3n = fmaf(ak, wcn, i3n);
      g3r = fmaf(hk, whr, g3r); g3z = fmaf(hk, whz, g3z); g3n = fmaf(hk, whn, g3n);
    }

    if (nb + 0 < n) {
      float r = 1.f / (1.f + __expf(-(i0r + g0r)));
      float z = 1.f / (1.f + __expf(-(i0z + g0z)));
      float nn = tanhf(fmaf(r, g0n, i0n));
      hout[(size_t)(nb + 0) * DF + lane] = fmaf(z, h0 - nn, nn);
    }
    if (nb + 1 < n) {
      float r = 1.f / (1.f + __expf(-(i1r + g1r)));
      float z = 1.f / (1.f + __expf(-(i1z + g1z)));
      float nn = tanhf(fmaf(r, g1n, i1n));
      hout[(size_t)(nb + 1) * DF + lane] = fmaf(z, h1 - nn, nn);
    }
    if (nb + 2 < n) {
      float r = 1.f / (1.f + __expf(-(i2r + g2r)));
      float z = 1.f / (1.f + __expf(-(i2z + g2z)));
      float nn = tanhf(fmaf(r, g2n, i2n));
      hout[(size_t)(nb + 2) * DF + lane] = fmaf(z, h2 - nn, nn);
    }
    if (nb + 3 < n) {
      float r = 1.f / (1.f + __expf(-(i3r + g3r)));
      float z = 1.f / (1.f + __expf(-(i3z + g3z)));
      float nn = tanhf(fmaf(r, g3n, i3n));
      hout[(size_t)(nb + 3) * DF + lane] = fmaf(z, h3 - nn, nn);
    }
  }
}

extern "C" void kernel_launch(void* const* d_in, const int* in_sizes, int n_in,
                              void* d_out, int out_size, void* d_ws, size_t ws_size,
                              hipStream_t stream) {
  const float* x   = (const float*)d_in[0];
  const int*   ei  = (const int*)d_in[1];
  const float* wgt = (const float*)d_in[2];
  const float* wih = (const float*)d_in[3];
  const float* whh = (const float*)d_in[4];
  const float* bih = (const float*)d_in[5];
  const float* bhh = (const float*)d_in[6];
  float* out = (float*)d_out;

  const int N = in_sizes[0] / DF;
  const int E = in_sizes[1] / 2;
  const int L = in_sizes[2] / (DF * DF);

  const int* srcv = ei;
  const int* dstv = ei + E;

  float* hA   = (float*)d_ws;
  float* hB   = hA + (size_t)N * DF;
  float* segH = hB + (size_t)N * DF;
  float* Wc   = segH + (size_t)N * DF;
  float* WhT  = Wc + (size_t)L * DF * 192;
  int* deg  = (int*)(WhT + DF * 192);
  int* rowp = deg + N;
  int* curs = rowp + (N + 1);
  int* csr  = curs + N;

  // CSR build (once per call; ws is re-poisoned every call)
  zero_int_kernel<<<(N + 255) / 256, 256, 0, stream>>>(deg, N);
  deg_kernel<<<(E + 255) / 256, 256, 0, stream>>>(dstv, deg, E);
  scan_kernel<<<1, 1024, 0, stream>>>(deg, rowp, curs, N);
  fill_kernel<<<(E + 255) / 256, 256, 0, stream>>>(srcv, dstv, curs, csr, E);

  // combined weights
  wc_kernel<<<(L * DF * 192 + 255) / 256, 256, 0, stream>>>(wgt, wih, Wc, L * DF * 192);
  wht_kernel<<<(DF * 192 + 255) / 256, 256, 0, stream>>>(whh, WhT);

  const float* hin = x;
  for (int i = 0; i < L; ++i) {
    gather_kernel<<<(N * DF + 255) / 256, 256, 0, stream>>>(hin, rowp, csr, segH, N);
    float* hout = (i == L - 1) ? out : ((i & 1) ? hB : hA);
    gru_kernel<<<256, 1024, 0, stream>>>(segH, hin, Wc + (size_t)i * DF * 192, WhT,
                                         bih, bhh, hout, N);
    hin = hout;
  }
}

// Round 3
// 517.576 us; speedup vs baseline: 1.6427x; 1.6427x over previous
//
#include <hip/hip_runtime.h>
#include <hip/hip_bf16.h>
#include <math.h>

#define DF 64

typedef __attribute__((ext_vector_type(8))) short short8v;   // 8 bf16 = 4 VGPRs
typedef __attribute__((ext_vector_type(4))) float f32x4;

__global__ __launch_bounds__(256) void zero_int_kernel(int* __restrict__ p, int n) {
  int i = blockIdx.x * 256 + threadIdx.x;
  if (i < n) p[i] = 0;
}

__global__ __launch_bounds__(256) void deg_kernel(const int* __restrict__ dst,
                                                  int* __restrict__ deg, int e) {
  int i = blockIdx.x * 256 + threadIdx.x;
  if (i < e) atomicAdd(&deg[dst[i]], 1);
}

// single-block exclusive scan over n counts -> rowp[0..n], also copies to curs
__global__ __launch_bounds__(1024) void scan_kernel(const int* __restrict__ deg,
                                                    int* __restrict__ rowp,
                                                    int* __restrict__ curs, int n) {
  __shared__ int a[1024];
  const int t = threadIdx.x;
  int carry = 0;
  for (int base = 0; base < n; base += 1024) {
    int i = base + t;
    int v = (i < n) ? deg[i] : 0;
    a[t] = v;
    __syncthreads();
    for (int off = 1; off < 1024; off <<= 1) {
      int addv = (t >= off) ? a[t - off] : 0;
      __syncthreads();
      a[t] += addv;
      __syncthreads();
    }
    if (i < n) {
      int excl = carry + a[t] - v;
      rowp[i] = excl;
      curs[i] = excl;
    }
    carry += a[1023];
    __syncthreads();
  }
  if (t == 0) rowp[n] = carry;
}

__global__ __launch_bounds__(256) void fill_kernel(const int* __restrict__ src,
                                                   const int* __restrict__ dst,
                                                   int* __restrict__ curs,
                                                   int* __restrict__ csr, int e) {
  int i = blockIdx.x * 256 + threadIdx.x;
  if (i < e) {
    int p = atomicAdd(&curs[dst[i]], 1);
    csr[p] = src[i];
  }
}

// Combined GEMM weights, bf16, layout WB[l][c][k], c in 0..255, k in 0..127.
//   c in [0,64):    r-gate combined:  k<64 -> Wc_r[k][f],  k>=64 -> w_hh[f][k-64]
//   c in [64,128):  z-gate combined:  k<64 -> Wc_z[k][f],  k>=64 -> w_hh[64+f][k-64]
//   c in [128,192): i_n only:         k<64 -> Wc_n[k][f],  k>=64 -> 0
//   c in [192,256): h_n only:         k<64 -> 0,           k>=64 -> w_hh[128+f][k-64]
// where Wc_g[k][f] = sum_t W[l][k][t] * w_ih[g*64+f][t]
__global__ __launch_bounds__(256) void wb_kernel(const float* __restrict__ W,
                                                 const float* __restrict__ wih,
                                                 const float* __restrict__ whh,
                                                 __hip_bfloat16* __restrict__ WB,
                                                 int total) {
  int idx = blockIdx.x * 256 + threadIdx.x;
  if (idx >= total) return;
  int k = idx & 127;
  int c = (idx >> 7) & 255;
  int l = idx >> 15;
  int g = c >> 6;   // 0:r 1:z 2:i_n 3:h_n
  int f = c & 63;
  float v = 0.f;
  if (k < 64) {
    if (g != 3) {
      int crow = (g == 0) ? f : (g == 1) ? (64 + f) : (128 + f);
      const float* wr = W + ((size_t)l * 64 + k) * 64;
      const float* ir = wih + (size_t)crow * 64;
      float s = 0.f;
#pragma unroll
      for (int t2 = 0; t2 < 64; ++t2) s = fmaf(wr[t2], ir[t2], s);
      v = s;
    }
  } else {
    if (g != 2) {
      int crow = (g == 0) ? f : (g == 1) ? (64 + f) : (128 + f);
      v = whh[(size_t)crow * 64 + (k - 64)];
    }
  }
  WB[idx] = __float2bfloat16(v);
}

__global__ __launch_bounds__(256) void cvt_kernel(const float* __restrict__ x,
                                                  __hip_bfloat16* __restrict__ o, int n) {
  int i = blockIdx.x * 256 + threadIdx.x;
  if (i < n) o[i] = __float2bfloat16(x[i]);
}

// one wave per node: segHb[n][lane] = bf16( sum over incoming edges of h[src][lane] )
__global__ __launch_bounds__(256) void gather_kernel(const float* __restrict__ h,
                                                     const int* __restrict__ rowp,
                                                     const int* __restrict__ csr,
                                                     __hip_bfloat16* __restrict__ segHb,
                                                     int n) {
  int gw = (int)((blockIdx.x * 256 + threadIdx.x) >> 6);
  int lane = threadIdx.x & 63;
  if (gw >= n) return;
  int beg = rowp[gw], end = rowp[gw + 1];
  float acc = 0.f;
  int e = beg;
  for (; e + 4 <= end; e += 4) {
    int s0 = csr[e], s1 = csr[e + 1], s2 = csr[e + 2], s3 = csr[e + 3];
    acc += h[(size_t)s0 * DF + lane] + h[(size_t)s1 * DF + lane] +
           h[(size_t)s2 * DF + lane] + h[(size_t)s3 * DF + lane];
  }
  for (; e < end; ++e) acc += h[(size_t)csr[e] * DF + lane];
  segHb[(size_t)gw * DF + lane] = __float2bfloat16(acc);
}

// swizzled LDS B-fragment read: element block (c, chunk) of WB_l[c][k]
// byte addr = c*256 + ((chunk ^ (c&15)) * 16)   (chunk = 16B block index along k)
__device__ __forceinline__ short8v ldB(const char* sB, int c, int chunk) {
  return *(const short8v*)(sB + c * 256 + ((chunk ^ (c & 15)) * 16));
}

#define MFMA(acc, a, b) acc = __builtin_amdgcn_mfma_f32_16x16x32_bf16(a, b, acc, 0, 0, 0)

// Fused GRU step via MFMA:
//   pre[N][256] = [segHb | hbf] (N x 128, bf16) @ WB (128 x 256, bf16)
//   r = sigmoid(pre[0:64]+bi_r+bh_r); z = sigmoid(pre[64:128]+bi_z+bh_z)
//   n = tanh(pre[128:192]+bi_n + r*(pre[192:256]+bh_n)); h' = n + z*(h-n)
__global__ __launch_bounds__(256, 2) void gru_mfma_kernel(
    const __hip_bfloat16* __restrict__ segHb, const float* __restrict__ hin,
    __hip_bfloat16* __restrict__ hbf,  // read (A k>=64) AND written in place (bf16 of h')
    const float* __restrict__ bih, const float* __restrict__ bhh,
    const __hip_bfloat16* __restrict__ WB, float* __restrict__ hout, int n) {
  __shared__ __hip_bfloat16 sB[256 * 128];  // 64 KiB, chunk-XOR swizzled
  // stage WB -> LDS (coalesced global reads, swizzled 16B ds writes)
#pragma unroll
  for (int i = 0; i < 16; ++i) {
    int idx = i * 256 + threadIdx.x;
    int c = idx >> 4, ch = idx & 15;
    short8v v = *(const short8v*)(WB + (size_t)c * 128 + ch * 8);
    *(short8v*)((char*)sB + c * 256 + ((ch ^ (c & 15)) * 16)) = v;
  }
  __syncthreads();

  const char* sBc = (const char*)sB;
  const int lane = threadIdx.x & 63;
  const int wid = threadIdx.x >> 6;
  const int row = lane & 15;     // node within 16-group (A); col within 16 (B/C)
  const int quad = lane >> 4;    // 0..3
  const int ch0 = quad, ch1 = 4 + quad, ch2 = 8 + quad, ch3 = 12 + quad;

  // biases per (j,row): f = j*16+row, hoisted out of node loop
  float bi_r[4], bi_z[4], bi_n[4], bh_r[4], bh_z[4], bh_n[4];
#pragma unroll
  for (int j = 0; j < 4; ++j) {
    int f = j * 16 + row;
    bi_r[j] = bih[f]; bi_z[j] = bih[64 + f]; bi_n[j] = bih[128 + f];
    bh_r[j] = bhh[f]; bh_z[j] = bhh[64 + f]; bh_n[j] = bhh[128 + f];
  }

  for (int nb0 = blockIdx.x * 64; nb0 < n; nb0 += gridDim.x * 64) {
    const int nb = nb0 + wid * 16;
    if (nb >= n) continue;
    // A fragments: k 0..63 from segHb row, k 64..127 from hbf row (8 contiguous k/lane)
    const short8v a0 = *(const short8v*)(segHb + (size_t)(nb + row) * DF + quad * 8);
    const short8v a1 = *(const short8v*)(segHb + (size_t)(nb + row) * DF + 32 + quad * 8);
    const short8v a2 = *(const short8v*)(hbf + (size_t)(nb + row) * DF + quad * 8);
    const short8v a3 = *(const short8v*)(hbf + (size_t)(nb + row) * DF + 32 + quad * 8);

    f32x4 accR[4], accZ[4], accN[4], accH[4];
#pragma unroll
    for (int j = 0; j < 4; ++j) {
      accR[j] = (f32x4){0.f, 0.f, 0.f, 0.f};
      accZ[j] = (f32x4){0.f, 0.f, 0.f, 0.f};
      accN[j] = (f32x4){0.f, 0.f, 0.f, 0.f};
      accH[j] = (f32x4){0.f, 0.f, 0.f, 0.f};
    }
    // B-fragment column is PER-LANE: c = block + row  (this was the R2 bug)
#pragma unroll
    for (int j = 0; j < 4; ++j) {
      MFMA(accR[j], a0, ldB(sBc, j * 16 + row, ch0));
      MFMA(accR[j], a1, ldB(sBc, j * 16 + row, ch1));
      MFMA(accR[j], a2, ldB(sBc, j * 16 + row, ch2));
      MFMA(accR[j], a3, ldB(sBc, j * 16 + row, ch3));
      MFMA(accZ[j], a0, ldB(sBc, 64 + j * 16 + row, ch0));
      MFMA(accZ[j], a1, ldB(sBc, 64 + j * 16 + row, ch1));
      MFMA(accZ[j], a2, ldB(sBc, 64 + j * 16 + row, ch2));
      MFMA(accZ[j], a3, ldB(sBc, 64 + j * 16 + row, ch3));
      MFMA(accN[j], a0, ldB(sBc, 128 + j * 16 + row, ch0));
      MFMA(accN[j], a1, ldB(sBc, 128 + j * 16 + row, ch1));
      MFMA(accH[j], a2, ldB(sBc, 192 + j * 16 + row, ch2));
      MFMA(accH[j], a3, ldB(sBc, 192 + j * 16 + row, ch3));
    }
    // epilogue: C layout col(lane&15)=feature-within-16, out-row = quad*4 + e = node
#pragma unroll
    for (int j = 0; j < 4; ++j) {
#pragma unroll
      for (int e = 0; e < 4; ++e) {
        const int node = nb + quad * 4 + e;
        const int f = j * 16 + row;
        const float hprev = hin[(size_t)node * DF + f];
        const float r = 1.f / (1.f + __expf(-(accR[j][e] + bi_r[j] + bh_r[j])));
        const float z = 1.f / (1.f + __expf(-(accZ[j][e] + bi_z[j] + bh_z[j])));
        const float nn = tanhf(accN[j][e] + bi_n[j] + r * (accH[j][e] + bh_n[j]));
        const float ho = fmaf(z, hprev - nn, nn);
        hout[(size_t)node * DF + f] = ho;
        hbf[(size_t)node * DF + f] = __float2bfloat16(ho);
      }
    }
  }
}

extern "C" void kernel_launch(void* const* d_in, const int* in_sizes, int n_in,
                              void* d_out, int out_size, void* d_ws, size_t ws_size,
                              hipStream_t stream) {
  const float* x   = (const float*)d_in[0];
  const int*   ei  = (const int*)d_in[1];
  const float* wgt = (const float*)d_in[2];
  const float* wih = (const float*)d_in[3];
  const float* whh = (const float*)d_in[4];
  const float* bih = (const float*)d_in[5];
  const float* bhh = (const float*)d_in[6];
  float* out = (float*)d_out;

  const int N = in_sizes[0] / DF;
  const int E = in_sizes[1] / 2;
  const int L = in_sizes[2] / (DF * DF);

  const int* srcv = ei;
  const int* dstv = ei + E;

  float* hA = (float*)d_ws;
  float* hB = hA + (size_t)N * DF;
  __hip_bfloat16* segHb = (__hip_bfloat16*)(hB + (size_t)N * DF);
  __hip_bfloat16* hbf   = segHb + (size_t)N * DF;
  __hip_bfloat16* WB    = hbf + (size_t)N * DF;
  int* deg  = (int*)(WB + (size_t)L * 256 * 128);
  int* rowp = deg + N;
  int* curs = rowp + (N + 1);
  int* csr  = curs + N;

  // CSR build (once per call; ws is re-poisoned every call)
  zero_int_kernel<<<(N + 255) / 256, 256, 0, stream>>>(deg, N);
  deg_kernel<<<(E + 255) / 256, 256, 0, stream>>>(dstv, deg, E);
  scan_kernel<<<1, 1024, 0, stream>>>(deg, rowp, curs, N);
  fill_kernel<<<(E + 255) / 256, 256, 0, stream>>>(srcv, dstv, curs, csr, E);

  // combined bf16 GEMM weights + bf16 copy of initial h
  wb_kernel<<<(L * 256 * 128 + 255) / 256, 256, 0, stream>>>(wgt, wih, whh, WB,
                                                             L * 256 * 128);
  cvt_kernel<<<(N * DF + 255) / 256, 256, 0, stream>>>(x, hbf, N * DF);

  const float* hin = x;
  const int gruGrid = (N + 63) / 64;
  for (int i = 0; i < L; ++i) {
    gather_kernel<<<(N * DF + 255) / 256, 256, 0, stream>>>(hin, rowp, csr, segHb, N);
    float* hout = (i == L - 1) ? out : ((i & 1) ? hB : hA);
    gru_mfma_kernel<<<gruGrid, 256, 0, stream>>>(segHb, hin, hbf, bih, bhh,
                                                 WB + (size_t)i * 256 * 128, hout, N);
    hin = hout;
  }
}

// Round 4
// 422.465 us; speedup vs baseline: 2.0125x; 1.2251x over previous
//
#include <hip/hip_runtime.h>
#include <hip/hip_bf16.h>
#include <math.h>

#define DF 64

typedef __attribute__((ext_vector_type(8))) short short8v;   // 8 bf16 = 4 VGPRs
typedef __attribute__((ext_vector_type(4))) float f32x4;

__global__ __launch_bounds__(256) void zero_int_kernel(int* __restrict__ p, int n) {
  int i = blockIdx.x * 256 + threadIdx.x;
  if (i < n) p[i] = 0;
}

__global__ __launch_bounds__(256) void deg_kernel(const int* __restrict__ dst,
                                                  int* __restrict__ deg, int e) {
  int i = blockIdx.x * 256 + threadIdx.x;
  if (i < e) atomicAdd(&deg[dst[i]], 1);
}

// hierarchical scan, stage 1: per-block (1024) exclusive scan + block sum
__global__ __launch_bounds__(1024) void scan_block_kernel(const int* __restrict__ deg,
                                                          int* __restrict__ part,
                                                          int* __restrict__ bsum, int n) {
  __shared__ int a[1024];
  const int t = threadIdx.x;
  const int i = blockIdx.x * 1024 + t;
  int v = (i < n) ? deg[i] : 0;
  a[t] = v;
  __syncthreads();
  for (int off = 1; off < 1024; off <<= 1) {
    int addv = (t >= off) ? a[t - off] : 0;
    __syncthreads();
    a[t] += addv;
    __syncthreads();
  }
  if (i < n) part[i] = a[t] - v;          // exclusive within block
  if (t == 1023) bsum[blockIdx.x] = a[1023];
}

// stage 2: single-wave exclusive scan of <=64 block sums; writes rowp[n]=total
__global__ __launch_bounds__(64) void scan_sums_kernel(const int* __restrict__ bsum,
                                                       int* __restrict__ boff,
                                                       int* __restrict__ rowp_last,
                                                       int nb) {
  const int t = threadIdx.x;
  int v = (t < nb) ? bsum[t] : 0;
  const int orig = v;
  for (int off = 1; off < 64; off <<= 1) {
    int u = __shfl_up(v, off);
    if (t >= off) v += u;
  }
  if (t < nb) boff[t] = v - orig;
  if (t == nb - 1) rowp_last[0] = v;
}

// stage 3: add block offsets
__global__ __launch_bounds__(256) void scan_apply_kernel(const int* __restrict__ part,
                                                         const int* __restrict__ boff,
                                                         int* __restrict__ rowp,
                                                         int* __restrict__ curs, int n) {
  int i = blockIdx.x * 256 + threadIdx.x;
  if (i < n) {
    int v = part[i] + boff[i >> 10];
    rowp[i] = v;
    curs[i] = v;
  }
}

__global__ __launch_bounds__(256) void fill_kernel(const int* __restrict__ src,
                                                   const int* __restrict__ dst,
                                                   int* __restrict__ curs,
                                                   int* __restrict__ csr, int e) {
  int i = blockIdx.x * 256 + threadIdx.x;
  if (i < e) {
    int p = atomicAdd(&curs[dst[i]], 1);
    csr[p] = src[i];
  }
}

// Combined GEMM weights, bf16, layout WB[l][c][k], c in 0..255, k in 0..127.
//   c in [0,64):    r-gate combined:  k<64 -> Wc_r[k][f],  k>=64 -> w_hh[f][k-64]
//   c in [64,128):  z-gate combined:  k<64 -> Wc_z[k][f],  k>=64 -> w_hh[64+f][k-64]
//   c in [128,192): i_n only:         k<64 -> Wc_n[k][f],  k>=64 -> 0
//   c in [192,256): h_n only:         k<64 -> 0,           k>=64 -> w_hh[128+f][k-64]
// where Wc_g[k][f] = sum_t W[l][k][t] * w_ih[g*64+f][t]
__global__ __launch_bounds__(256) void wb_kernel(const float* __restrict__ W,
                                                 const float* __restrict__ wih,
                                                 const float* __restrict__ whh,
                                                 __hip_bfloat16* __restrict__ WB,
                                                 int total) {
  int idx = blockIdx.x * 256 + threadIdx.x;
  if (idx >= total) return;
  int k = idx & 127;
  int c = (idx >> 7) & 255;
  int l = idx >> 15;
  int g = c >> 6;   // 0:r 1:z 2:i_n 3:h_n
  int f = c & 63;
  float v = 0.f;
  if (k < 64) {
    if (g != 3) {
      int crow = (g == 0) ? f : (g == 1) ? (64 + f) : (128 + f);
      const float* wr = W + ((size_t)l * 64 + k) * 64;
      const float* ir = wih + (size_t)crow * 64;
      float s = 0.f;
#pragma unroll
      for (int t2 = 0; t2 < 64; ++t2) s = fmaf(wr[t2], ir[t2], s);
      v = s;
    }
  } else {
    if (g != 2) {
      int crow = (g == 0) ? f : (g == 1) ? (64 + f) : (128 + f);
      v = whh[(size_t)crow * 64 + (k - 64)];
    }
  }
  WB[idx] = __float2bfloat16(v);
}

__global__ __launch_bounds__(256) void cvt_kernel(const float* __restrict__ x,
                                                  __hip_bfloat16* __restrict__ o, int n) {
  int i = blockIdx.x * 256 + threadIdx.x;
  if (i < n) o[i] = __float2bfloat16(x[i]);
}

// one wave per node: segHb[n][lane] = bf16( sum over incoming edges of hb[src][lane] )
// reads bf16 rows (128 B/edge) -- half the traffic of the fp32 version
__global__ __launch_bounds__(256) void gather_kernel(const __hip_bfloat16* __restrict__ hb,
                                                     const int* __restrict__ rowp,
                                                     const int* __restrict__ csr,
                                                     __hip_bfloat16* __restrict__ segHb,
                                                     int n) {
  int gw = (int)((blockIdx.x * 256 + threadIdx.x) >> 6);
  int lane = threadIdx.x & 63;
  if (gw >= n) return;
  int beg = rowp[gw], end = rowp[gw + 1];
  float acc = 0.f;
  int e = beg;
  for (; e + 4 <= end; e += 4) {
    int s0 = csr[e], s1 = csr[e + 1], s2 = csr[e + 2], s3 = csr[e + 3];
    float v0 = __bfloat162float(hb[(size_t)s0 * DF + lane]);
    float v1 = __bfloat162float(hb[(size_t)s1 * DF + lane]);
    float v2 = __bfloat162float(hb[(size_t)s2 * DF + lane]);
    float v3 = __bfloat162float(hb[(size_t)s3 * DF + lane]);
    acc += v0 + v1 + v2 + v3;
  }
  for (; e < end; ++e) acc += __bfloat162float(hb[(size_t)csr[e] * DF + lane]);
  segHb[(size_t)gw * DF + lane] = __float2bfloat16(acc);
}

// swizzled LDS B-fragment read: element block (c, chunk) of WB_l[c][k]
// byte addr = c*256 + ((chunk ^ (c&15)) * 16)   (chunk = 16B block index along k)
__device__ __forceinline__ short8v ldB(const char* sB, int c, int chunk) {
  return *(const short8v*)(sB + c * 256 + ((chunk ^ (c & 15)) * 16));
}

#define MFMA(acc, a, b) acc = __builtin_amdgcn_mfma_f32_16x16x32_bf16(a, b, acc, 0, 0, 0)

// Fused GRU step via MFMA:
//   pre[N][256] = [segHb | hbf] (N x 128, bf16) @ WB (128 x 256, bf16)
//   r = sigmoid(pre[0:64]+bi_r+bh_r); z = sigmoid(pre[64:128]+bi_z+bh_z)
//   n = tanh(pre[128:192]+bi_n + r*(pre[192:256]+bh_n)); h' = n + z*(h-n)
__global__ __launch_bounds__(256, 2) void gru_mfma_kernel(
    const __hip_bfloat16* __restrict__ segHb, const float* __restrict__ hin,
    __hip_bfloat16* __restrict__ hbf,  // read (A k>=64) AND written in place (bf16 of h')
    const float* __restrict__ bih, const float* __restrict__ bhh,
    const __hip_bfloat16* __restrict__ WB, float* __restrict__ hout, int n) {
  __shared__ __hip_bfloat16 sB[256 * 128];  // 64 KiB, chunk-XOR swizzled
  // stage WB -> LDS (coalesced global reads, swizzled 16B ds writes)
#pragma unroll
  for (int i = 0; i < 16; ++i) {
    int idx = i * 256 + threadIdx.x;
    int c = idx >> 4, ch = idx & 15;
    short8v v = *(const short8v*)(WB + (size_t)c * 128 + ch * 8);
    *(short8v*)((char*)sB + c * 256 + ((ch ^ (c & 15)) * 16)) = v;
  }
  __syncthreads();

  const char* sBc = (const char*)sB;
  const int lane = threadIdx.x & 63;
  const int wid = threadIdx.x >> 6;
  const int row = lane & 15;     // node within 16-group (A); col within 16 (B/C)
  const int quad = lane >> 4;    // 0..3
  const int ch0 = quad, ch1 = 4 + quad, ch2 = 8 + quad, ch3 = 12 + quad;

  float bi_r[4], bi_z[4], bi_n[4], bh_r[4], bh_z[4], bh_n[4];
#pragma unroll
  for (int j = 0; j < 4; ++j) {
    int f = j * 16 + row;
    bi_r[j] = bih[f]; bi_z[j] = bih[64 + f]; bi_n[j] = bih[128 + f];
    bh_r[j] = bhh[f]; bh_z[j] = bhh[64 + f]; bh_n[j] = bhh[128 + f];
  }

  for (int nb0 = blockIdx.x * 64; nb0 < n; nb0 += gridDim.x * 64) {
    const int nb = nb0 + wid * 16;
    if (nb >= n) continue;
    const short8v a0 = *(const short8v*)(segHb + (size_t)(nb + row) * DF + quad * 8);
    const short8v a1 = *(const short8v*)(segHb + (size_t)(nb + row) * DF + 32 + quad * 8);
    const short8v a2 = *(const short8v*)(hbf + (size_t)(nb + row) * DF + quad * 8);
    const short8v a3 = *(const short8v*)(hbf + (size_t)(nb + row) * DF + 32 + quad * 8);

    f32x4 accR[4], accZ[4], accN[4], accH[4];
#pragma unroll
    for (int j = 0; j < 4; ++j) {
      accR[j] = (f32x4){0.f, 0.f, 0.f, 0.f};
      accZ[j] = (f32x4){0.f, 0.f, 0.f, 0.f};
      accN[j] = (f32x4){0.f, 0.f, 0.f, 0.f};
      accH[j] = (f32x4){0.f, 0.f, 0.f, 0.f};
    }
    // B-fragment column is PER-LANE: c = block + row
#pragma unroll
    for (int j = 0; j < 4; ++j) {
      MFMA(accR[j], a0, ldB(sBc, j * 16 + row, ch0));
      MFMA(accR[j], a1, ldB(sBc, j * 16 + row, ch1));
      MFMA(accR[j], a2, ldB(sBc, j * 16 + row, ch2));
      MFMA(accR[j], a3, ldB(sBc, j * 16 + row, ch3));
      MFMA(accZ[j], a0, ldB(sBc, 64 + j * 16 + row, ch0));
      MFMA(accZ[j], a1, ldB(sBc, 64 + j * 16 + row, ch1));
      MFMA(accZ[j], a2, ldB(sBc, 64 + j * 16 + row, ch2));
      MFMA(accZ[j], a3, ldB(sBc, 64 + j * 16 + row, ch3));
      MFMA(accN[j], a0, ldB(sBc, 128 + j * 16 + row, ch0));
      MFMA(accN[j], a1, ldB(sBc, 128 + j * 16 + row, ch1));
      MFMA(accH[j], a2, ldB(sBc, 192 + j * 16 + row, ch2));
      MFMA(accH[j], a3, ldB(sBc, 192 + j * 16 + row, ch3));
    }
    // epilogue: C layout col(lane&15)=feature-within-16, out-row = quad*4 + e = node
#pragma unroll
    for (int j = 0; j < 4; ++j) {
#pragma unroll
      for (int e = 0; e < 4; ++e) {
        const int node = nb + quad * 4 + e;
        const int f = j * 16 + row;
        const float hprev = hin[(size_t)node * DF + f];
        const float r = 1.f / (1.f + __expf(-(accR[j][e] + bi_r[j] + bh_r[j])));
        const float z = 1.f / (1.f + __expf(-(accZ[j][e] + bi_z[j] + bh_z[j])));
        const float nn = tanhf(accN[j][e] + bi_n[j] + r * (accH[j][e] + bh_n[j]));
        const float ho = fmaf(z, hprev - nn, nn);
        hout[(size_t)node * DF + f] = ho;
        hbf[(size_t)node * DF + f] = __float2bfloat16(ho);
      }
    }
  }
}

extern "C" void kernel_launch(void* const* d_in, const int* in_sizes, int n_in,
                              void* d_out, int out_size, void* d_ws, size_t ws_size,
                              hipStream_t stream) {
  const float* x   = (const float*)d_in[0];
  const int*   ei  = (const int*)d_in[1];
  const float* wgt = (const float*)d_in[2];
  const float* wih = (const float*)d_in[3];
  const float* whh = (const float*)d_in[4];
  const float* bih = (const float*)d_in[5];
  const float* bhh = (const float*)d_in[6];
  float* out = (float*)d_out;

  const int N = in_sizes[0] / DF;
  const int E = in_sizes[1] / 2;
  const int L = in_sizes[2] / (DF * DF);

  const int* srcv = ei;
  const int* dstv = ei + E;

  float* hA = (float*)d_ws;
  float* hB = hA + (size_t)N * DF;
  __hip_bfloat16* segHb = (__hip_bfloat16*)(hB + (size_t)N * DF);
  __hip_bfloat16* hbf   = segHb + (size_t)N * DF;
  __hip_bfloat16* WB    = hbf + (size_t)N * DF;
  int* deg  = (int*)(WB + (size_t)L * 256 * 128);
  int* rowp = deg + N;
  int* curs = rowp + (N + 1);
  int* csr  = curs + N;
  int* part = csr + E;
  int* bsum = part + N;
  int* boff = bsum + 64;

  const int NB = (N + 1023) / 1024;  // 49 for N=50000 (must be <= 64)

  // CSR build (once per call; ws is re-poisoned every call)
  zero_int_kernel<<<(N + 255) / 256, 256, 0, stream>>>(deg, N);
  deg_kernel<<<(E + 255) / 256, 256, 0, stream>>>(dstv, deg, E);
  scan_block_kernel<<<NB, 1024, 0, stream>>>(deg, part, bsum, N);
  scan_sums_kernel<<<1, 64, 0, stream>>>(bsum, boff, rowp + N, NB);
  scan_apply_kernel<<<(N + 255) / 256, 256, 0, stream>>>(part, boff, rowp, curs, N);
  fill_kernel<<<(E + 255) / 256, 256, 0, stream>>>(srcv, dstv, curs, csr, E);

  // combined bf16 GEMM weights + bf16 copy of initial h
  wb_kernel<<<(L * 256 * 128 + 255) / 256, 256, 0, stream>>>(wgt, wih, whh, WB,
                                                             L * 256 * 128);
  cvt_kernel<<<(N * DF + 255) / 256, 256, 0, stream>>>(x, hbf, N * DF);

  const float* hin = x;
  const int gruGrid = (N + 63) / 64;
  for (int i = 0; i < L; ++i) {
    gather_kernel<<<(N * DF + 255) / 256, 256, 0, stream>>>(hbf, rowp, csr, segHb, N);
    float* hout = (i == L - 1) ? out : ((i & 1) ? hB : hA);
    gru_mfma_kernel<<<gruGrid, 256, 0, stream>>>(segHb, hin, hbf, bih, bhh,
                                                 WB + (size_t)i * 256 * 128, hout, N);
    hin = hout;
  }
}